// Round 1
// 213.803 us; speedup vs baseline: 1.0901x; 1.0901x over previous
//
#include <hip/hip_runtime.h>

// ---------------------------------------------------------------------------
// GCN 2-layer forward, round 13.
// Round-12 post-mortem: 233.1 us, k_agg 2x46.4. k_agg counters: HBM 28%,
// MfmaUtil 0, VALUBusy 55% (gfx94x 4cyc formula; real ~27% on SIMD-32).
// -> latency + instruction-overhead bound. Audit: ~4.8M wave-instrs of
// cross-lane shuffle reduction (48/node) + 31% sentinel-pad slots (pad-16).
// Round-13 delta:
//   * k_agg REWRITE: one node per 8-lane group (8 nodes/wave). Feature dim
//     = 8 lanes x uint4 -> accumulators lane-private, NO cross-lane
//     reduction. Pad-to-2 instead of pad-to-16 (cnt now stores
//     (cval+1)&~1; offsets stay 16-aligned). csrc int2 stream prefetched
//     1-deep; 32-bit H offsets for saddr-form loads.
//   * k_bfill: 391 blocks x 256 thr (~6 waves/CU) -> 1024 thr/block.
//   * k_gemm: 512 -> 1024 blocks; k_part: PTILE 4096 -> 2048.
// Pipeline: binit, part, bfill, gemm1, agg1, gemm2, agg2 (7 kernels).
// ---------------------------------------------------------------------------

#define NPB 32       // nodes per block (agg): 256 thr / 8-lane groups
#define BSH 8        // bucket shift: 256 nodes per bucket
#define BSZ 256
#define PTILE 2048   // messages per partition tile
#define CAP 6144     // fixed bucket capacity (slots), multiple of 16
#define PADALLOW 3856  // per-bucket csrc pad allowance (256*15 + 16)
#define CROW (CAP + PADALLOW)  // per-bucket csrc region

typedef __attribute__((ext_vector_type(8))) short bf16x8;
typedef __attribute__((ext_vector_type(4))) float f32x4;

__device__ __forceinline__ unsigned bf16_rne(float f) {
    unsigned b = __float_as_uint(f);
    return (b + 0x7fffu + ((b >> 16) & 1u)) >> 16;
}
__device__ __forceinline__ float bf16_lo(unsigned u) { return __uint_as_float(u << 16); }
__device__ __forceinline__ float bf16_hi(unsigned u) { return __uint_as_float(u & 0xffff0000u); }

__global__ void k_binit(int* __restrict__ bcur, int NB) {
    int b = blockIdx.x * blockDim.x + threadIdx.x;
    if (b < NB) bcur[b] = b * CAP;
}

// Block-staged partition: one tile of PTILE messages per block iteration.
// Reserves contiguous ranges in fixed-capacity bucket regions via bcur.
__global__ __launch_bounds__(256) void k_part(const int* __restrict__ rowi,
                                              const int* __restrict__ coli,
                                              int E, int N, int NB, int numTiles,
                                              int* __restrict__ bcur,
                                              unsigned* __restrict__ pairs) {
    __shared__ int hist[512];
    __shared__ int base[512];
    int t = threadIdx.x;
    int T = E + N;
    for (int tile = blockIdx.x; tile < numTiles; tile += gridDim.x) {
        int tstart = tile * PTILE;
        int m = min(PTILE, T - tstart);
        for (int b = t; b < NB; b += 256) hist[b] = 0;
        __syncthreads();
        for (int i = t; i < m; i += 256) {
            int g = tstart + i;
            int c = (g < E) ? coli[g] : (g - E);
            atomicAdd(&hist[c >> BSH], 1);
        }
        __syncthreads();
        for (int b = t; b < NB; b += 256) {
            int h = hist[b];
            base[b] = h ? atomicAdd(&bcur[b], h) : 0;
            hist[b] = 0;  // reuse as local cursor
        }
        __syncthreads();
        for (int i = t; i < m; i += 256) {
            int g = tstart + i;
            int r, c;
            if (g < E) { r = rowi[g]; c = coli[g]; }
            else       { r = g - E; c = r; }  // self loop
            int b = c >> BSH;
            int rank = atomicAdd(&hist[b], 1);
            pairs[base[b] + rank] = (unsigned)r | ((unsigned)(c & (BSZ - 1)) << 24);
        }
        __syncthreads();
    }
}

// One block per bucket (1024 threads): histogram its <=256 nodes, scan PADDED
// counts (16-aligned offsets), emit CSR meta (cnt = true count rounded to x2),
// fill csrc + sentinel pads. Message count for bucket b = bcur[b] - b*CAP.
__global__ __launch_bounds__(1024) void k_bfill(const unsigned* __restrict__ pairs,
                                                const int* __restrict__ bcur,
                                                int N,
                                                int* __restrict__ offsets,
                                                int* __restrict__ cnt,
                                                float* __restrict__ dinv,
                                                int* __restrict__ csrc) {
    __shared__ int scnt[BSZ];
    __shared__ int scur[BSZ];
    __shared__ int wsum[4];
    int b = blockIdx.x;
    int t = threadIdx.x;
    int ebeg = b * CAP;
    int m = bcur[b] - ebeg;
    int pbase = b * CROW;  // 16-aligned per-bucket csrc region base
    if (t < BSZ) scnt[t] = 0;
    __syncthreads();
    for (int i = t; i < m; i += 1024) {
        atomicAdd(&scnt[pairs[ebeg + i] >> 24], 1);
    }
    __syncthreads();
    int cval = 0, pc = 0, inc = 0;
    int lane = t & 63, wid = t >> 6;
    if (t < BSZ) {
        cval = scnt[t];                 // true msg count (incl. self loop)
        pc = (cval + 15) & ~15;         // offset padding: multiple of 16
        inc = pc;
        #pragma unroll
        for (int d = 1; d < 64; d <<= 1) {
            int o = __shfl_up(inc, d);
            if (lane >= d) inc += o;
        }
        if (lane == 63) wsum[wid] = inc;
    }
    __syncthreads();
    if (t < BSZ) {
        int woff = 0;
        for (int i = 0; i < wid; i++) woff += wsum[i];
        int off = pbase + woff + inc - pc;  // padded CSR offset for node (b<<BSH)+t
        int v = (b << BSH) + t;
        if (v < N) {
            offsets[v] = off;
            cnt[v] = (cval + 1) & ~1;       // round to x2 for int2 agg loop
            dinv[v] = rsqrtf((float)cval);  // cval >= 1 (self loop)
        }
        scur[t] = off;
        // sentinel pads (read H row N == zeros)
        for (int i = off + cval; i < off + pc; i++) csrc[i] = N;
    }
    __syncthreads();
    for (int i = t; i < m; i += 1024) {
        unsigned pk = pairs[ebeg + i];
        int slot = atomicAdd(&scur[pk >> 24], 1);
        csrc[slot] = (int)(pk & 0xFFFFFFu);
    }
}

// H[row] = dinv[row] * (X[row] @ W) via mfma_f32_16x16x32_bf16.
// Also writes an all-zero row at index N (sentinel target for csrc pads).
template <bool BF16IN>
__global__ __launch_bounds__(256) void k_gemm(const void* __restrict__ Xv,
                                              const float* __restrict__ W,
                                              const float* __restrict__ dinv,
                                              unsigned* __restrict__ Hout,
                                              int N, int nSlabs, int slabStride) {
    __shared__ float SMEM[4224];  // 4096 W staging, then 4 x (16x66) transpose
    int t = threadIdx.x;
    int lane = t & 63, w = t >> 6;
    int nn = lane & 15, kq = lane >> 4;

    for (int i = t; i < 1024; i += 256) ((float4*)SMEM)[i] = ((const float4*)W)[i];
    __syncthreads();
    bf16x8 Bf[2][4];
    #pragma unroll
    for (int kt = 0; kt < 2; kt++) {
        #pragma unroll
        for (int ct = 0; ct < 4; ct++) {
            union { bf16x8 v; unsigned short s[8]; } u;
            #pragma unroll
            for (int j = 0; j < 8; j++) {
                int k = kt * 32 + kq * 8 + j;
                u.s[j] = (unsigned short)bf16_rne(SMEM[k * 64 + ct * 16 + nn]);
            }
            Bf[kt][ct] = u.v;
        }
    }
    __syncthreads();  // W region dead; SMEM becomes transpose scratch

    float* outT = SMEM + w * 1056;  // 16 rows x 66 floats

    for (int slab = blockIdx.x * 4 + w; slab < nSlabs; slab += slabStride) {
        int row0 = slab * 16;
        int rowA = min(row0 + nn, N - 1);
        bf16x8 A0, A1;
        if (BF16IN) {
            const uint4* X = (const uint4*)Xv;  // row = 8 uint4
            union { uint4 u; bf16x8 v; } a0, a1;
            a0.u = X[(size_t)rowA * 8 + kq];
            a1.u = X[(size_t)rowA * 8 + 4 + kq];
            A0 = a0.v; A1 = a1.v;
        } else {
            const float4* X = (const float4*)Xv;  // row = 16 float4
            float4 f0 = X[(size_t)rowA * 16 + kq * 2];
            float4 f1 = X[(size_t)rowA * 16 + kq * 2 + 1];
            float4 f2 = X[(size_t)rowA * 16 + 8 + kq * 2];
            float4 f3 = X[(size_t)rowA * 16 + 8 + kq * 2 + 1];
            union { bf16x8 v; unsigned short s[8]; } a0, a1;
            a0.s[0] = (unsigned short)bf16_rne(f0.x); a0.s[1] = (unsigned short)bf16_rne(f0.y);
            a0.s[2] = (unsigned short)bf16_rne(f0.z); a0.s[3] = (unsigned short)bf16_rne(f0.w);
            a0.s[4] = (unsigned short)bf16_rne(f1.x); a0.s[5] = (unsigned short)bf16_rne(f1.y);
            a0.s[6] = (unsigned short)bf16_rne(f1.z); a0.s[7] = (unsigned short)bf16_rne(f1.w);
            a1.s[0] = (unsigned short)bf16_rne(f2.x); a1.s[1] = (unsigned short)bf16_rne(f2.y);
            a1.s[2] = (unsigned short)bf16_rne(f2.z); a1.s[3] = (unsigned short)bf16_rne(f2.w);
            a1.s[4] = (unsigned short)bf16_rne(f3.x); a1.s[5] = (unsigned short)bf16_rne(f3.y);
            a1.s[6] = (unsigned short)bf16_rne(f3.z); a1.s[7] = (unsigned short)bf16_rne(f3.w);
            A0 = a0.v; A1 = a1.v;
        }
        float dvm = dinv[rowA];

        f32x4 acc[4];
        #pragma unroll
        for (int ct = 0; ct < 4; ct++) acc[ct] = (f32x4){0.f, 0.f, 0.f, 0.f};
        #pragma unroll
        for (int ct = 0; ct < 4; ct++) {
            acc[ct] = __builtin_amdgcn_mfma_f32_16x16x32_bf16(A0, Bf[0][ct], acc[ct], 0, 0, 0);
            acc[ct] = __builtin_amdgcn_mfma_f32_16x16x32_bf16(A1, Bf[1][ct], acc[ct], 0, 0, 0);
        }

        #pragma unroll
        for (int reg = 0; reg < 4; reg++) {
            int r = kq * 4 + reg;
            float dv = __shfl(dvm, r);  // lane r holds dinv[row0+r]
            #pragma unroll
            for (int ct = 0; ct < 4; ct++) {
                outT[r * 66 + ct * 16 + nn] = acc[ct][reg] * dv;
            }
        }
        int rr = lane >> 2;        // 4 lanes per row
        int c0 = (lane & 3) * 16;  // 16 cols per lane
        int orow = row0 + rr;
        if (orow < N) {
            unsigned pk[8];
            #pragma unroll
            for (int i = 0; i < 8; i++) {
                float lo = outT[rr * 66 + c0 + 2 * i];
                float hi = outT[rr * 66 + c0 + 2 * i + 1];
                pk[i] = bf16_rne(lo) | (bf16_rne(hi) << 16);
            }
            uint4* dst = (uint4*)Hout + (size_t)orow * 8 + (lane & 3) * 2;
            dst[0] = make_uint4(pk[0], pk[1], pk[2], pk[3]);
            dst[1] = make_uint4(pk[4], pk[5], pk[6], pk[7]);
        } else if (orow == N) {  // zero sentinel row
            uint4* dst = (uint4*)Hout + (size_t)N * 8 + (lane & 3) * 2;
            dst[0] = make_uint4(0, 0, 0, 0);
            dst[1] = make_uint4(0, 0, 0, 0);
        }
    }
}

// out[v] = epi( dinv[v] * sum_{j in CSR[v]} H[src_j] + bias )
// One node per 8-lane group (8 nodes per wave, 32 per block).
// Lane fl = t&7 owns feats 8*fl..8*fl+7 (one uint4 of the bf16 row) ->
// accumulators are lane-private, no cross-lane reduction. csrc consumed as
// an int2 stream (cnt rounded to x2, sentinel row N = zeros), prefetched
// 1-deep. 32-bit byte offsets into H for saddr-form loads.
template <bool RELU_BF16OUT>
__global__ __launch_bounds__(256) void k_agg(const uint4* __restrict__ H,
                                             const int* __restrict__ offsets,
                                             const int* __restrict__ cnt,
                                             const int* __restrict__ csrc,
                                             const float* __restrict__ dinv,
                                             const float* __restrict__ bias,
                                             void* __restrict__ outv, int N) {
    int t = threadIdx.x;
    int fl = t & 7;                       // feature group: feats 8*fl..8*fl+7
    int v = blockIdx.x * NPB + (t >> 3);
    if (v >= N) return;
    int beg = offsets[v];                 // 16-aligned
    int deg = cnt[v];                     // true count rounded up to x2
    const int2* cs2 = (const int2*)(csrc + beg);
    const char* hb = (const char*)H + ((unsigned)fl << 4);

    float a0 = 0.f, a1 = 0.f, a2 = 0.f, a3 = 0.f;
    float a4 = 0.f, a5 = 0.f, a6 = 0.f, a7 = 0.f;

#define ACC8(R) do {                                                        \
        uint4 dd = *(const uint4*)(hb + ((unsigned)(R) << 7));              \
        a0 += bf16_lo(dd.x); a1 += bf16_hi(dd.x);                           \
        a2 += bf16_lo(dd.y); a3 += bf16_hi(dd.y);                           \
        a4 += bf16_lo(dd.z); a5 += bf16_hi(dd.z);                           \
        a6 += bf16_lo(dd.w); a7 += bf16_hi(dd.w);                           \
    } while (0)

    int2 ss = cs2[0];                     // deg >= 2 always (self loop + pad)
    for (int j = 2; j < deg; j += 2) {
        int2 nx = cs2[j >> 1];            // independent: issues before adds
        ACC8(ss.x);
        ACC8(ss.y);
        ss = nx;
    }
    ACC8(ss.x);
    ACC8(ss.y);
#undef ACC8

    float dv = dinv[v];
    const float4* b4 = (const float4*)bias;
    float4 bA = b4[fl * 2];
    float4 bB = b4[fl * 2 + 1];
    float r0 = fmaf(dv, a0, bA.x);
    float r1 = fmaf(dv, a1, bA.y);
    float r2 = fmaf(dv, a2, bA.z);
    float r3 = fmaf(dv, a3, bA.w);
    float r4 = fmaf(dv, a4, bB.x);
    float r5 = fmaf(dv, a5, bB.y);
    float r6 = fmaf(dv, a6, bB.z);
    float r7 = fmaf(dv, a7, bB.w);
    if (RELU_BF16OUT) {
        r0 = fmaxf(r0, 0.f); r1 = fmaxf(r1, 0.f);
        r2 = fmaxf(r2, 0.f); r3 = fmaxf(r3, 0.f);
        r4 = fmaxf(r4, 0.f); r5 = fmaxf(r5, 0.f);
        r6 = fmaxf(r6, 0.f); r7 = fmaxf(r7, 0.f);
        uint4 pk;
        pk.x = bf16_rne(r0) | (bf16_rne(r1) << 16);
        pk.y = bf16_rne(r2) | (bf16_rne(r3) << 16);
        pk.z = bf16_rne(r4) | (bf16_rne(r5) << 16);
        pk.w = bf16_rne(r6) | (bf16_rne(r7) << 16);
        ((uint4*)outv)[(size_t)v * 8 + fl] = pk;
    } else {
        float4* o = (float4*)outv + (size_t)v * 16 + fl * 2;
        o[0] = make_float4(r0, r1, r2, r3);
        o[1] = make_float4(r4, r5, r6, r7);
    }
}

extern "C" void kernel_launch(void* const* d_in, const int* in_sizes, int n_in,
                              void* d_out, int out_size, void* d_ws, size_t ws_size,
                              hipStream_t stream) {
    const float* x  = (const float*)d_in[0];
    const int*   ei = (const int*)d_in[1];  // harness delivers int32
    const float* W1 = (const float*)d_in[2];
    const float* b1 = (const float*)d_in[3];
    const float* W2 = (const float*)d_in[4];
    const float* b2 = (const float*)d_in[5];
    float* out      = (float*)d_out;

    const int N = in_sizes[0] / 64;
    const int E = in_sizes[1] / 2;
    const int* row = ei;
    const int* col = ei + E;
    const int T = E + N;
    const int NB = (N + BSZ - 1) >> BSH;  // buckets

    char* p = (char*)d_ws;
    auto alloc = [&](size_t bytes) { void* r = (void*)p; p += (bytes + 255) & ~(size_t)255; return r; };
    int*      bcur    = (int*)alloc((size_t)(NB + 1) * 4);
    int*      offsets = (int*)alloc((size_t)N * 4);
    int*      cnt     = (int*)alloc((size_t)N * 4);
    float*    dinv    = (float*)alloc((size_t)N * 4);
    unsigned* pairs   = (unsigned*)alloc((size_t)NB * CAP * 4);
    int*      csrc    = (int*)alloc(((size_t)NB * CROW + 64) * 4);
    unsigned* hbuf    = (unsigned*)alloc((size_t)(N + 16) * 32 * 4);  // bf16, +zero row
    unsigned* abuf    = (unsigned*)alloc((size_t)(N + 16) * 32 * 4);  // bf16, +zero row

    const int numTiles = (T + PTILE - 1) / PTILE;

    k_binit<<<(NB + 255) / 256, 256, 0, stream>>>(bcur, NB);
    k_part<<<numTiles, 256, 0, stream>>>(row, col, E, N, NB, numTiles, bcur, pairs);
    k_bfill<<<NB, 1024, 0, stream>>>(pairs, bcur, N, offsets, cnt, dinv, csrc);

    const int nSlabs = (N + 16) / 16;  // covers zero sentinel row N
    const int GEMM_BLOCKS = 1024;      // 4 waves each
    const int SLAB_STRIDE = GEMM_BLOCKS * 4;
    const int GB = (N + NPB - 1) / NPB;

    k_gemm<false><<<GEMM_BLOCKS, 256, 0, stream>>>(x, W1, dinv, hbuf, N, nSlabs, SLAB_STRIDE);
    k_agg<true><<<GB, 256, 0, stream>>>((const uint4*)hbuf, offsets, cnt, csrc, dinv, b1, abuf, N);
    k_gemm<true><<<GEMM_BLOCKS, 256, 0, stream>>>(abuf, W2, dinv, hbuf, N, nSlabs, SLAB_STRIDE);
    k_agg<false><<<GB, 256, 0, stream>>>((const uint4*)hbuf, offsets, cnt, csrc, dinv, b2, out, N);
}

// Round 2
// 201.336 us; speedup vs baseline: 1.1576x; 1.0619x over previous
//
#include <hip/hip_runtime.h>

// ---------------------------------------------------------------------------
// GCN 2-layer forward, round 14.
// Round-13 post-mortem: WIN 233->213.8us. k_agg group-per-node rewrite worked
// (k_agg out of top-5). New top: k_part 45.9us with HBM 10.8%, VALU 2.1%,
// occ 24% -> serialization chain, not a pipe. Diagnosis: per-tile bucket
// reservation = 830 tiles x atomicAdd on the SAME 391 global counters
// (16/cache-line) -> ~830 serialized atomic rounds per address.
// Round-14 delta (k_part only, rest byte-identical):
//   * PTILE 2048 -> 8192, 512 thr/block: 830 -> 208 reservation rounds.
//   * bcur padded to 1 counter / 64B line (stride 16): no same-line L2
//     serialization across buckets.
//   * col staged in LDS (32KB) during histogram pass: scatter pass no longer
//     re-reads coli from global. LDS 36KB -> 4 blocks/CU = 32 waves/CU.
// Pipeline: binit, part, bfill, gemm1, agg1, gemm2, agg2 (7 kernels).
// ---------------------------------------------------------------------------

#define NPB 32       // nodes per block (agg): 256 thr / 8-lane groups
#define BSH 8        // bucket shift: 256 nodes per bucket
#define BSZ 256
#define PTILE 8192   // messages per partition tile
#define CAP 6144     // fixed bucket capacity (slots), multiple of 16
#define PADALLOW 3856  // per-bucket csrc pad allowance (256*15 + 16)
#define CROW (CAP + PADALLOW)  // per-bucket csrc region

typedef __attribute__((ext_vector_type(8))) short bf16x8;
typedef __attribute__((ext_vector_type(4))) float f32x4;

__device__ __forceinline__ unsigned bf16_rne(float f) {
    unsigned b = __float_as_uint(f);
    return (b + 0x7fffu + ((b >> 16) & 1u)) >> 16;
}
__device__ __forceinline__ float bf16_lo(unsigned u) { return __uint_as_float(u << 16); }
__device__ __forceinline__ float bf16_hi(unsigned u) { return __uint_as_float(u & 0xffff0000u); }

__global__ void k_binit(int* __restrict__ bcur, int NB) {
    int b = blockIdx.x * blockDim.x + threadIdx.x;
    if (b < NB) bcur[b << 4] = b * CAP;  // one counter per 64B line
}

// Block-staged partition: one tile of PTILE messages per block iteration.
// Reserves contiguous ranges in fixed-capacity bucket regions via bcur.
// col staged in LDS so the scatter pass does not re-read global coli.
__global__ __launch_bounds__(512) void k_part(const int* __restrict__ rowi,
                                              const int* __restrict__ coli,
                                              int E, int N, int NB, int numTiles,
                                              int* __restrict__ bcur,
                                              unsigned* __restrict__ pairs) {
    __shared__ int hist[512];
    __shared__ int base[512];
    __shared__ int scol[PTILE];
    int t = threadIdx.x;
    int T = E + N;
    for (int tile = blockIdx.x; tile < numTiles; tile += gridDim.x) {
        int tstart = tile * PTILE;
        int m = min(PTILE, T - tstart);
        for (int b = t; b < NB; b += 512) hist[b] = 0;
        __syncthreads();
        for (int i = t; i < m; i += 512) {
            int g = tstart + i;
            int c = (g < E) ? coli[g] : (g - E);
            scol[i] = c;
            atomicAdd(&hist[c >> BSH], 1);
        }
        __syncthreads();
        for (int b = t; b < NB; b += 512) {
            int h = hist[b];
            base[b] = h ? atomicAdd(&bcur[b << 4], h) : 0;
            hist[b] = 0;  // reuse as local cursor
        }
        __syncthreads();
        for (int i = t; i < m; i += 512) {
            int g = tstart + i;
            int c = scol[i];
            int r = (g < E) ? rowi[g] : c;  // self-loop tail has r == c
            int b = c >> BSH;
            int rank = atomicAdd(&hist[b], 1);
            pairs[base[b] + rank] = (unsigned)r | ((unsigned)(c & (BSZ - 1)) << 24);
        }
        __syncthreads();
    }
}

// One block per bucket (1024 threads): histogram its <=256 nodes, scan PADDED
// counts (16-aligned offsets), emit CSR meta (cnt = true count rounded to x2),
// fill csrc + sentinel pads. Message count for bucket b = bcur[b<<4] - b*CAP.
__global__ __launch_bounds__(1024) void k_bfill(const unsigned* __restrict__ pairs,
                                                const int* __restrict__ bcur,
                                                int N,
                                                int* __restrict__ offsets,
                                                int* __restrict__ cnt,
                                                float* __restrict__ dinv,
                                                int* __restrict__ csrc) {
    __shared__ int scnt[BSZ];
    __shared__ int scur[BSZ];
    __shared__ int wsum[4];
    int b = blockIdx.x;
    int t = threadIdx.x;
    int ebeg = b * CAP;
    int m = bcur[b << 4] - ebeg;
    int pbase = b * CROW;  // 16-aligned per-bucket csrc region base
    if (t < BSZ) scnt[t] = 0;
    __syncthreads();
    for (int i = t; i < m; i += 1024) {
        atomicAdd(&scnt[pairs[ebeg + i] >> 24], 1);
    }
    __syncthreads();
    int cval = 0, pc = 0, inc = 0;
    int lane = t & 63, wid = t >> 6;
    if (t < BSZ) {
        cval = scnt[t];                 // true msg count (incl. self loop)
        pc = (cval + 15) & ~15;         // offset padding: multiple of 16
        inc = pc;
        #pragma unroll
        for (int d = 1; d < 64; d <<= 1) {
            int o = __shfl_up(inc, d);
            if (lane >= d) inc += o;
        }
        if (lane == 63) wsum[wid] = inc;
    }
    __syncthreads();
    if (t < BSZ) {
        int woff = 0;
        for (int i = 0; i < wid; i++) woff += wsum[i];
        int off = pbase + woff + inc - pc;  // padded CSR offset for node (b<<BSH)+t
        int v = (b << BSH) + t;
        if (v < N) {
            offsets[v] = off;
            cnt[v] = (cval + 1) & ~1;       // round to x2 for int2 agg loop
            dinv[v] = rsqrtf((float)cval);  // cval >= 1 (self loop)
        }
        scur[t] = off;
        // sentinel pads (read H row N == zeros)
        for (int i = off + cval; i < off + pc; i++) csrc[i] = N;
    }
    __syncthreads();
    for (int i = t; i < m; i += 1024) {
        unsigned pk = pairs[ebeg + i];
        int slot = atomicAdd(&scur[pk >> 24], 1);
        csrc[slot] = (int)(pk & 0xFFFFFFu);
    }
}

// H[row] = dinv[row] * (X[row] @ W) via mfma_f32_16x16x32_bf16.
// Also writes an all-zero row at index N (sentinel target for csrc pads).
template <bool BF16IN>
__global__ __launch_bounds__(256) void k_gemm(const void* __restrict__ Xv,
                                              const float* __restrict__ W,
                                              const float* __restrict__ dinv,
                                              unsigned* __restrict__ Hout,
                                              int N, int nSlabs, int slabStride) {
    __shared__ float SMEM[4224];  // 4096 W staging, then 4 x (16x66) transpose
    int t = threadIdx.x;
    int lane = t & 63, w = t >> 6;
    int nn = lane & 15, kq = lane >> 4;

    for (int i = t; i < 1024; i += 256) ((float4*)SMEM)[i] = ((const float4*)W)[i];
    __syncthreads();
    bf16x8 Bf[2][4];
    #pragma unroll
    for (int kt = 0; kt < 2; kt++) {
        #pragma unroll
        for (int ct = 0; ct < 4; ct++) {
            union { bf16x8 v; unsigned short s[8]; } u;
            #pragma unroll
            for (int j = 0; j < 8; j++) {
                int k = kt * 32 + kq * 8 + j;
                u.s[j] = (unsigned short)bf16_rne(SMEM[k * 64 + ct * 16 + nn]);
            }
            Bf[kt][ct] = u.v;
        }
    }
    __syncthreads();  // W region dead; SMEM becomes transpose scratch

    float* outT = SMEM + w * 1056;  // 16 rows x 66 floats

    for (int slab = blockIdx.x * 4 + w; slab < nSlabs; slab += slabStride) {
        int row0 = slab * 16;
        int rowA = min(row0 + nn, N - 1);
        bf16x8 A0, A1;
        if (BF16IN) {
            const uint4* X = (const uint4*)Xv;  // row = 8 uint4
            union { uint4 u; bf16x8 v; } a0, a1;
            a0.u = X[(size_t)rowA * 8 + kq];
            a1.u = X[(size_t)rowA * 8 + 4 + kq];
            A0 = a0.v; A1 = a1.v;
        } else {
            const float4* X = (const float4*)Xv;  // row = 16 float4
            float4 f0 = X[(size_t)rowA * 16 + kq * 2];
            float4 f1 = X[(size_t)rowA * 16 + kq * 2 + 1];
            float4 f2 = X[(size_t)rowA * 16 + 8 + kq * 2];
            float4 f3 = X[(size_t)rowA * 16 + 8 + kq * 2 + 1];
            union { bf16x8 v; unsigned short s[8]; } a0, a1;
            a0.s[0] = (unsigned short)bf16_rne(f0.x); a0.s[1] = (unsigned short)bf16_rne(f0.y);
            a0.s[2] = (unsigned short)bf16_rne(f0.z); a0.s[3] = (unsigned short)bf16_rne(f0.w);
            a0.s[4] = (unsigned short)bf16_rne(f1.x); a0.s[5] = (unsigned short)bf16_rne(f1.y);
            a0.s[6] = (unsigned short)bf16_rne(f1.z); a0.s[7] = (unsigned short)bf16_rne(f1.w);
            a1.s[0] = (unsigned short)bf16_rne(f2.x); a1.s[1] = (unsigned short)bf16_rne(f2.y);
            a1.s[2] = (unsigned short)bf16_rne(f2.z); a1.s[3] = (unsigned short)bf16_rne(f2.w);
            a1.s[4] = (unsigned short)bf16_rne(f3.x); a1.s[5] = (unsigned short)bf16_rne(f3.y);
            a1.s[6] = (unsigned short)bf16_rne(f3.z); a1.s[7] = (unsigned short)bf16_rne(f3.w);
            A0 = a0.v; A1 = a1.v;
        }
        float dvm = dinv[rowA];

        f32x4 acc[4];
        #pragma unroll
        for (int ct = 0; ct < 4; ct++) acc[ct] = (f32x4){0.f, 0.f, 0.f, 0.f};
        #pragma unroll
        for (int ct = 0; ct < 4; ct++) {
            acc[ct] = __builtin_amdgcn_mfma_f32_16x16x32_bf16(A0, Bf[0][ct], acc[ct], 0, 0, 0);
            acc[ct] = __builtin_amdgcn_mfma_f32_16x16x32_bf16(A1, Bf[1][ct], acc[ct], 0, 0, 0);
        }

        #pragma unroll
        for (int reg = 0; reg < 4; reg++) {
            int r = kq * 4 + reg;
            float dv = __shfl(dvm, r);  // lane r holds dinv[row0+r]
            #pragma unroll
            for (int ct = 0; ct < 4; ct++) {
                outT[r * 66 + ct * 16 + nn] = acc[ct][reg] * dv;
            }
        }
        int rr = lane >> 2;        // 4 lanes per row
        int c0 = (lane & 3) * 16;  // 16 cols per lane
        int orow = row0 + rr;
        if (orow < N) {
            unsigned pk[8];
            #pragma unroll
            for (int i = 0; i < 8; i++) {
                float lo = outT[rr * 66 + c0 + 2 * i];
                float hi = outT[rr * 66 + c0 + 2 * i + 1];
                pk[i] = bf16_rne(lo) | (bf16_rne(hi) << 16);
            }
            uint4* dst = (uint4*)Hout + (size_t)orow * 8 + (lane & 3) * 2;
            dst[0] = make_uint4(pk[0], pk[1], pk[2], pk[3]);
            dst[1] = make_uint4(pk[4], pk[5], pk[6], pk[7]);
        } else if (orow == N) {  // zero sentinel row
            uint4* dst = (uint4*)Hout + (size_t)N * 8 + (lane & 3) * 2;
            dst[0] = make_uint4(0, 0, 0, 0);
            dst[1] = make_uint4(0, 0, 0, 0);
        }
    }
}

// out[v] = epi( dinv[v] * sum_{j in CSR[v]} H[src_j] + bias )
// One node per 8-lane group (8 nodes per wave, 32 per block).
// Lane fl = t&7 owns feats 8*fl..8*fl+7 (one uint4 of the bf16 row) ->
// accumulators are lane-private, no cross-lane reduction. csrc consumed as
// an int2 stream (cnt rounded to x2, sentinel row N = zeros), prefetched
// 1-deep. 32-bit byte offsets into H for saddr-form loads.
template <bool RELU_BF16OUT>
__global__ __launch_bounds__(256) void k_agg(const uint4* __restrict__ H,
                                             const int* __restrict__ offsets,
                                             const int* __restrict__ cnt,
                                             const int* __restrict__ csrc,
                                             const float* __restrict__ dinv,
                                             const float* __restrict__ bias,
                                             void* __restrict__ outv, int N) {
    int t = threadIdx.x;
    int fl = t & 7;                       // feature group: feats 8*fl..8*fl+7
    int v = blockIdx.x * NPB + (t >> 3);
    if (v >= N) return;
    int beg = offsets[v];                 // 16-aligned
    int deg = cnt[v];                     // true count rounded up to x2
    const int2* cs2 = (const int2*)(csrc + beg);
    const char* hb = (const char*)H + ((unsigned)fl << 4);

    float a0 = 0.f, a1 = 0.f, a2 = 0.f, a3 = 0.f;
    float a4 = 0.f, a5 = 0.f, a6 = 0.f, a7 = 0.f;

#define ACC8(R) do {                                                        \
        uint4 dd = *(const uint4*)(hb + ((unsigned)(R) << 7));              \
        a0 += bf16_lo(dd.x); a1 += bf16_hi(dd.x);                           \
        a2 += bf16_lo(dd.y); a3 += bf16_hi(dd.y);                           \
        a4 += bf16_lo(dd.z); a5 += bf16_hi(dd.z);                           \
        a6 += bf16_lo(dd.w); a7 += bf16_hi(dd.w);                           \
    } while (0)

    int2 ss = cs2[0];                     // deg >= 2 always (self loop + pad)
    for (int j = 2; j < deg; j += 2) {
        int2 nx = cs2[j >> 1];            // independent: issues before adds
        ACC8(ss.x);
        ACC8(ss.y);
        ss = nx;
    }
    ACC8(ss.x);
    ACC8(ss.y);
#undef ACC8

    float dv = dinv[v];
    const float4* b4 = (const float4*)bias;
    float4 bA = b4[fl * 2];
    float4 bB = b4[fl * 2 + 1];
    float r0 = fmaf(dv, a0, bA.x);
    float r1 = fmaf(dv, a1, bA.y);
    float r2 = fmaf(dv, a2, bA.z);
    float r3 = fmaf(dv, a3, bA.w);
    float r4 = fmaf(dv, a4, bB.x);
    float r5 = fmaf(dv, a5, bB.y);
    float r6 = fmaf(dv, a6, bB.z);
    float r7 = fmaf(dv, a7, bB.w);
    if (RELU_BF16OUT) {
        r0 = fmaxf(r0, 0.f); r1 = fmaxf(r1, 0.f);
        r2 = fmaxf(r2, 0.f); r3 = fmaxf(r3, 0.f);
        r4 = fmaxf(r4, 0.f); r5 = fmaxf(r5, 0.f);
        r6 = fmaxf(r6, 0.f); r7 = fmaxf(r7, 0.f);
        uint4 pk;
        pk.x = bf16_rne(r0) | (bf16_rne(r1) << 16);
        pk.y = bf16_rne(r2) | (bf16_rne(r3) << 16);
        pk.z = bf16_rne(r4) | (bf16_rne(r5) << 16);
        pk.w = bf16_rne(r6) | (bf16_rne(r7) << 16);
        ((uint4*)outv)[(size_t)v * 8 + fl] = pk;
    } else {
        float4* o = (float4*)outv + (size_t)v * 16 + fl * 2;
        o[0] = make_float4(r0, r1, r2, r3);
        o[1] = make_float4(r4, r5, r6, r7);
    }
}

extern "C" void kernel_launch(void* const* d_in, const int* in_sizes, int n_in,
                              void* d_out, int out_size, void* d_ws, size_t ws_size,
                              hipStream_t stream) {
    const float* x  = (const float*)d_in[0];
    const int*   ei = (const int*)d_in[1];  // harness delivers int32
    const float* W1 = (const float*)d_in[2];
    const float* b1 = (const float*)d_in[3];
    const float* W2 = (const float*)d_in[4];
    const float* b2 = (const float*)d_in[5];
    float* out      = (float*)d_out;

    const int N = in_sizes[0] / 64;
    const int E = in_sizes[1] / 2;
    const int* row = ei;
    const int* col = ei + E;
    const int T = E + N;
    const int NB = (N + BSZ - 1) >> BSH;  // buckets

    char* p = (char*)d_ws;
    auto alloc = [&](size_t bytes) { void* r = (void*)p; p += (bytes + 255) & ~(size_t)255; return r; };
    int*      bcur    = (int*)alloc((size_t)(NB * 16 + 16) * 4);  // 1 counter / 64B line
    int*      offsets = (int*)alloc((size_t)N * 4);
    int*      cnt     = (int*)alloc((size_t)N * 4);
    float*    dinv    = (float*)alloc((size_t)N * 4);
    unsigned* pairs   = (unsigned*)alloc((size_t)NB * CAP * 4);
    int*      csrc    = (int*)alloc(((size_t)NB * CROW + 64) * 4);
    unsigned* hbuf    = (unsigned*)alloc((size_t)(N + 16) * 32 * 4);  // bf16, +zero row
    unsigned* abuf    = (unsigned*)alloc((size_t)(N + 16) * 32 * 4);  // bf16, +zero row

    const int numTiles = (T + PTILE - 1) / PTILE;

    k_binit<<<(NB + 255) / 256, 256, 0, stream>>>(bcur, NB);
    k_part<<<numTiles, 512, 0, stream>>>(row, col, E, N, NB, numTiles, bcur, pairs);
    k_bfill<<<NB, 1024, 0, stream>>>(pairs, bcur, N, offsets, cnt, dinv, csrc);

    const int nSlabs = (N + 16) / 16;  // covers zero sentinel row N
    const int GEMM_BLOCKS = 1024;      // 4 waves each
    const int SLAB_STRIDE = GEMM_BLOCKS * 4;
    const int GB = (N + NPB - 1) / NPB;

    k_gemm<false><<<GEMM_BLOCKS, 256, 0, stream>>>(x, W1, dinv, hbuf, N, nSlabs, SLAB_STRIDE);
    k_agg<true><<<GB, 256, 0, stream>>>((const uint4*)hbuf, offsets, cnt, csrc, dinv, b1, abuf, N);
    k_gemm<true><<<GEMM_BLOCKS, 256, 0, stream>>>(abuf, W2, dinv, hbuf, N, nSlabs, SLAB_STRIDE);
    k_agg<false><<<GB, 256, 0, stream>>>((const uint4*)hbuf, offsets, cnt, csrc, dinv, b2, out, N);
}